// Round 15
// baseline (163.249 us; speedup 1.0000x reference)
//
#include <hip/hip_runtime.h>

// HausdorffLoss (average): B=8, N=M=4096, C=128, fp32 in/out.
// R19b: R19 with the prep_b compile fix (store pack8 result through
// bf16x8*, not ushort8* — vector elem signedness mismatch). Design
// unchanged:
// R15 core (best measured: 111.4us) + targeted trims. R18's fusion
// failed for identified reasons: (a) swizzled ds_write_b128 staging = 8-way
// WRITE bank conflicts (1.6M counted; R15's gl2lds writes are linear), and
// (b) B conversion is shared by 16 x-blocks -> fusing it multiplied the
// work 16x (FETCH 37->83MB). Lesson: fold in only block-PRIVATE work.
//   1) mfma loop = R15 verbatim (gl2lds B staging, LDS-atomic colmax,
//      bhalf in LDS, e-trick).
//   2) bfA dropped: A frags convert from fp32 S1 in-kernel (R18's A-phase,
//      proven correct; one-time, block-private). Prep handles ONLY B:
//      ~25MB HBM vs ~50 -> ~4-5us.
//   3) reduce merged into mfma tail via last-block-per-batch (threadfence +
//      atomicAdd counter, 64 blocks/batch; counter zeroed in prep).
//      Removes one dispatch + launch gap.
// Fill note: harness re-poisons 256MiB ws (~44us/iter) - uncontrollable.
#define B_ 8
#define N_ 4096
#define M_ 4096
#define C_ 128
#define BN_ (B_ * N_)
#define BM_ (B_ * M_)

typedef __attribute__((ext_vector_type(8))) short bf16x8;    // MFMA A/B frag
typedef __attribute__((ext_vector_type(4))) float floatx4;   // MFMA C/D frag
typedef __attribute__((ext_vector_type(8))) unsigned short ushort8;

// fp32 -> bf16 round-to-nearest-even
__device__ __forceinline__ unsigned short f2bf(float x) {
    unsigned int u = __float_as_uint(x);
    u += 0x7FFFu + ((u >> 16) & 1u);
    return (unsigned short)(u >> 16);
}

// pack 8 f32 (two float4) -> bf16x8
__device__ __forceinline__ bf16x8 pack8(float4 a, float4 b) {
    ushort8 o;
    o[0] = f2bf(a.x); o[1] = f2bf(a.y); o[2] = f2bf(a.z); o[3] = f2bf(a.w);
    o[4] = f2bf(b.x); o[5] = f2bf(b.y); o[6] = f2bf(b.z); o[7] = f2bf(b.w);
    return *(bf16x8*)&o;
}

// monotone float->uint order map (works for mixed signs, no NaN inputs)
__device__ __forceinline__ unsigned fkey(float f) {
    unsigned u = __float_as_uint(f);
    return u ^ (unsigned)(((int)u >> 31) | 0x80000000);
}
__device__ __forceinline__ float funkey(unsigned k) {
    unsigned u = (k & 0x80000000u) ? (k ^ 0x80000000u) : ~k;
    return __uint_as_float(u);
}

// async global->LDS, 16 B per lane; LDS dest = wave-uniform base + lane*16
__device__ __forceinline__ void gl2lds16(const void* g, void* l) {
    __builtin_amdgcn_global_load_lds(
        (const __attribute__((address_space(1))) void*)g,
        (__attribute__((address_space(3))) void*)l, 16, 0, 0);
}

// ---------------------------------------------------------------------------
// Prep (B only): bf16 convert (swizzled: bfB[col][g ^ (col&15)] = src[col][g]),
// norms[col] = -0.5 * ||col||^2; zero the last-block counters.
// Grid = BM_/64 = 512 blocks x 256 threads; 4 cols/wave/step, 4 steps.
// ---------------------------------------------------------------------------
__global__ __launch_bounds__(256) void prep_b(
    const float* __restrict__ S2, float* __restrict__ norms,
    unsigned short* __restrict__ bfB, unsigned int* __restrict__ cnt) {
    const int lane = threadIdx.x & 63;
    const int w    = threadIdx.x >> 6;
    const int r4   = lane >> 4;
    const int g4   = lane & 15;

    #pragma unroll
    for (int step = 0; step < 4; ++step) {
        const int row = blockIdx.x * 64 + step * 16 + w * 4 + r4;  // 0..32767

        const float* src = S2 + (size_t)row * C_;
        float4 v0 = ((const float4*)src)[g4 * 2];
        float4 v1 = ((const float4*)src)[g4 * 2 + 1];

        float s = v0.x*v0.x + v0.y*v0.y + v0.z*v0.z + v0.w*v0.w
                + v1.x*v1.x + v1.y*v1.y + v1.z*v1.z + v1.w*v1.w;
        s += __shfl_xor(s, 1, 64);
        s += __shfl_xor(s, 2, 64);
        s += __shfl_xor(s, 4, 64);
        s += __shfl_xor(s, 8, 64);

        unsigned short* dst = bfB + (size_t)row * C_;
        *(bf16x8*)&dst[(g4 ^ (row & 15)) * 8] = pack8(v0, v1);

        if (g4 == 0) norms[row] = -0.5f * s;
    }
    if (blockIdx.x == 0 && threadIdx.x < B_) cnt[threadIdx.x] = 0u;
}

// ---------------------------------------------------------------------------
// Main: grid (N/256, M/1024, B). 4 waves; wave = its 64 rows x all 64 tile
// cols. A frags direct from fp32 S1 (in-reg convert + norms). R15 K-loop.
// Tail: last block per batch reduces rowpart/colpart -> out[b].
// ---------------------------------------------------------------------------
__global__ __launch_bounds__(256, 2) void hausdorff_mfma(
    const float* __restrict__ S1, const unsigned short* __restrict__ Bbf,
    const float* __restrict__ bhalf_g, float* __restrict__ rowpart,
    float* __restrict__ colpart, unsigned int* __restrict__ cnt,
    float* __restrict__ out) {

    __shared__ unsigned short B_lds[2][64 * 128];   // 2 x 16 KB
    __shared__ unsigned int colmax_u[1024][4];      // 16 KB keys [col][quad]
    __shared__ float bhalf_lds[1024];               // 4 KB
    __shared__ float ascr[256];                     // 1 KB row-norm scratch
    __shared__ float ws4[4];
    __shared__ int islast;

    const int b     = blockIdx.z;
    const int x     = blockIdx.x;
    const int panel = blockIdx.y;                   // cols panel*1024 ..
    const int row0  = x * 256;
    const int tid   = threadIdx.x;
    const int lane  = tid & 63;
    const int w     = tid >> 6;
    const int lm    = lane & 15;
    const int quad  = lane >> 4;
    const int wrow  = w * 64;                       // wave's 64-row slice

    const unsigned short* Bws = Bbf + ((size_t)b * M_ + (size_t)panel * 1024) * C_;

    // init colmax keys to 0 (== -inf under the order map)
    {
        uint4 z; z.x = z.y = z.z = z.w = 0u;
        unsigned int* cm = &colmax_u[0][0];
        #pragma unroll
        for (int k = 0; k < 4; ++k)
            *(uint4*)&cm[tid * 16 + k * 4] = z;
    }

    // stage bhalf panel (1024 f32 = 4 KB): 1 gl2lds16 per thread
    gl2lds16(bhalf_g + (size_t)b * M_ + panel * 1024 + w * 256 + lane * 4,
             &bhalf_lds[w * 256]);

    // A phase: fp32 frags -> bf16 regs + row norms (one-time, block-private)
    const float* As = S1 + ((size_t)b * N_ + row0 + wrow) * C_;
    bf16x8 af[4][4];
    #pragma unroll
    for (int i = 0; i < 4; ++i) {
        float ss = 0.f;
        #pragma unroll
        for (int c = 0; c < 4; ++c) {
            // frag (i,c): row wrow+16i+lm, k = c*32 + quad*8 .. +7
            const float* p = As + (size_t)(16 * i + lm) * C_ + c * 32 + quad * 8;
            float4 u0 = *(const float4*)p;
            float4 u1 = *(const float4*)(p + 4);
            ss += u0.x*u0.x + u0.y*u0.y + u0.z*u0.z + u0.w*u0.w
                + u1.x*u1.x + u1.y*u1.y + u1.z*u1.z + u1.w*u1.w;
            af[i][c] = pack8(u0, u1);
        }
        ss += __shfl_xor(ss, 16, 64);
        ss += __shfl_xor(ss, 32, 64);
        if (quad == 0) ascr[wrow + 16 * i + lm] = -0.5f * ss;
    }

    // stage B tile 0 into buf0 (16 KB: 4 waves x 4 gl2lds)
    #pragma unroll
    for (int k = 0; k < 4; ++k) {
        const int off = w * 2048 + k * 512;
        gl2lds16(Bws + off + lane * 8, &B_lds[0][off]);
    }

    __syncthreads();   // colmax init + ascr + bhalf + tile0 staged

    // ha in acc layout: rows wrow + 16i + 4*quad + r
    float ha[16];
    #pragma unroll
    for (int i = 0; i < 4; ++i) {
        float4 t = *(const float4*)&ascr[wrow + 16 * i + 4 * quad];
        ha[4*i+0] = t.x; ha[4*i+1] = t.y; ha[4*i+2] = t.z; ha[4*i+3] = t.w;
    }

    float rv[16];                                   // running e-max per row
    #pragma unroll
    for (int v = 0; v < 16; ++v) rv[v] = -1e30f;

    for (int it = 0; it < 16; ++it) {
        const int cur = it & 1;
        if (it) __syncthreads();   // tile `it` staged (loads >= 1 iter old)

        if (it < 15) {     // stage next tile into the other buffer
            const unsigned short* Bt = Bws + (size_t)(it + 1) * 64 * C_;
            #pragma unroll
            for (int k = 0; k < 4; ++k) {
                const int off = w * 2048 + k * 512;
                gl2lds16(Bt + off + lane * 8, &B_lds[cur ^ 1][off]);
            }
        }

        float hb[4];
        #pragma unroll
        for (int j = 0; j < 4; ++j)
            hb[j] = bhalf_lds[it * 64 + 16 * j + lm];   // bcast ds_read_b32

        // acc init = ha + hb  ->  acc accumulates to  inner - (sa+sb)/2
        floatx4 acc[4][4];
        #pragma unroll
        for (int i = 0; i < 4; ++i)
            #pragma unroll
            for (int j = 0; j < 4; ++j)
                #pragma unroll
                for (int r = 0; r < 4; ++r)
                    acc[i][j][r] = ha[4 * i + r] + hb[j];

        // two j-halves to cap bf register pressure (32 regs, reused)
        #pragma unroll
        for (int h = 0; h < 2; ++h) {
            bf16x8 bfr[2][4];
            #pragma unroll
            for (int j2 = 0; j2 < 2; ++j2)
                #pragma unroll
                for (int c = 0; c < 4; ++c)
                    bfr[j2][c] = *(const bf16x8*)
                        &B_lds[cur][(16 * (2 * h + j2) + lm) * 128 +
                                    (((c * 4 + quad) ^ lm) * 8)];
            #pragma unroll
            for (int c = 0; c < 4; ++c)
                #pragma unroll
                for (int i = 0; i < 4; ++i)
                    #pragma unroll
                    for (int j2 = 0; j2 < 2; ++j2)
                        acc[i][2 * h + j2] = __builtin_amdgcn_mfma_f32_16x16x32_bf16(
                            af[i][c], bfr[j2][c], acc[i][2 * h + j2], 0, 0, 0);
        }

        // row-max update (max over the 4 j-groups per row-element)
        #pragma unroll
        for (int i = 0; i < 4; ++i)
            #pragma unroll
            for (int r = 0; r < 4; ++r) {
                float m01 = fmaxf(acc[i][0][r], acc[i][1][r]);
                float m23 = fmaxf(acc[i][2][r], acc[i][3][r]);
                rv[4 * i + r] = fmaxf(rv[4 * i + r], fmaxf(m01, m23));
            }

        // col-max per j-group: in-lane tree + fire-and-forget LDS atomicMax
        #pragma unroll
        for (int j = 0; j < 4; ++j) {
            float t0 = fmaxf(fmaxf(acc[0][j][0], acc[0][j][1]),
                             fmaxf(acc[0][j][2], acc[0][j][3]));
            float t1 = fmaxf(fmaxf(acc[1][j][0], acc[1][j][1]),
                             fmaxf(acc[1][j][2], acc[1][j][3]));
            float t2 = fmaxf(fmaxf(acc[2][j][0], acc[2][j][1]),
                             fmaxf(acc[2][j][2], acc[2][j][3]));
            float t3 = fmaxf(fmaxf(acc[3][j][0], acc[3][j][1]),
                             fmaxf(acc[3][j][2], acc[3][j][3]));
            float cv = fmaxf(fmaxf(t0, t1), fmaxf(t2, t3));
            atomicMax(&colmax_u[it * 64 + 16 * j + lm][quad], fkey(cv));
        }
    }

    // row maxes: butterfly across the 16 lane-cols; waves own disjoint rows
    #pragma unroll
    for (int s = 1; s < 16; s <<= 1)
        #pragma unroll
        for (int v = 0; v < 16; ++v)
            rv[v] = fmaxf(rv[v], __shfl_xor(rv[v], s, 64));
    if (lm == 0) {
        #pragma unroll
        for (int v = 0; v < 16; ++v)
            rowpart[((size_t)panel * B_ + b) * N_ + row0 + wrow +
                    16 * (v >> 2) + 4 * quad + (v & 3)] = rv[v];
    }

    __syncthreads();   // all colmax atomics done

    // flush col partials: 4 cols/thread, decode keys, float4 store
    {
        const int c0 = tid * 4;
        float cout[4];
        #pragma unroll
        for (int cc = 0; cc < 4; ++cc) {
            uint4 q = *(const uint4*)&colmax_u[c0 + cc][0];
            unsigned k = max(max(q.x, q.y), max(q.z, q.w));
            cout[cc] = funkey(k);
        }
        *(float4*)&colpart[((size_t)x * B_ + b) * M_ + (size_t)panel * 1024 + c0] =
            *(float4*)cout;
    }

    // ---- last-block-per-batch reduction (replaces the reduce dispatch) ----
    __threadfence();                    // release rowpart/colpart stores
    if (tid == 0) islast = (atomicAdd(&cnt[b], 1u) == 63u);
    __syncthreads();
    if (!islast) return;
    __threadfence();                    // acquire other blocks' stores

    float s = 0.f;
    for (int i = tid; i < N_; i += 256) {
        float ra = fmaxf(rowpart[((size_t)0 * B_ + b) * N_ + i],
                         rowpart[((size_t)1 * B_ + b) * N_ + i]);
        float rb = fmaxf(rowpart[((size_t)2 * B_ + b) * N_ + i],
                         rowpart[((size_t)3 * B_ + b) * N_ + i]);
        float rm = fmaxf(ra, rb);
        float ca = -1e30f, cb = -1e30f;
        #pragma unroll
        for (int xx = 0; xx < 16; xx += 2) {
            ca = fmaxf(ca, colpart[((size_t)xx * B_ + b) * M_ + i]);
            cb = fmaxf(cb, colpart[((size_t)(xx + 1) * B_ + b) * M_ + i]);
        }
        float cm = fmaxf(ca, cb);
        s += sqrtf(fmaxf(-2.f * rm, 0.f)) * (1.f / N_)
           + sqrtf(fmaxf(-2.f * cm, 0.f)) * (1.f / M_);
    }
    #pragma unroll
    for (int off = 32; off > 0; off >>= 1) s += __shfl_down(s, off, 64);
    if ((tid & 63) == 0) ws4[tid >> 6] = s;
    __syncthreads();
    if (tid == 0) out[b] = ws4[0] + ws4[1] + ws4[2] + ws4[3];
}

extern "C" void kernel_launch(void* const* d_in, const int* in_sizes, int n_in,
                              void* d_out, int out_size, void* d_ws, size_t ws_size,
                              hipStream_t stream) {
    const float* s1 = (const float*)d_in[0];
    const float* s2 = (const float*)d_in[1];
    float* out = (float*)d_out;

    // ws: bnorms(BM f32, -0.5x) | bfB | rowpart[4][B][N] | colpart[16][B][M]
    //     | cnt[8]
    float* bnorms        = (float*)d_ws;
    unsigned short* bfB  = (unsigned short*)(bnorms + BM_);
    float* rowpart       = (float*)(bfB + (size_t)BM_ * C_);
    float* colpart       = rowpart + (size_t)4 * B_ * N_;
    unsigned int* cnt    = (unsigned int*)(colpart + (size_t)16 * B_ * M_);

    prep_b<<<BM_ / 64, 256, 0, stream>>>(s2, bnorms, bfB, cnt);

    dim3 grid(N_ / 256, M_ / 1024, B_);
    hausdorff_mfma<<<grid, 256, 0, stream>>>(
        s1, bfB, bnorms, rowpart, colpart, cnt, out);
}